// Round 9
// baseline (1492.078 us; speedup 1.0000x reference)
//
#include <hip/hip_runtime.h>
#include <hip/hip_bf16.h>

// R-GCN (2-layer) + mean-pool + linear + softmax, MI355X.
// v3: dst-sorted gather with LDS-staged swizzled W. Round-5/8 rocprof showed
// the atomic path bound by device-scope fp32 RMW (WRITE_SIZE == 400MB payload
// @ ~2TB/s); v2's msg buffer (450MB) exceeded ws (fallback ran in round 8).
// v3 removes BOTH: counting-sort edges by dst; each wave owns a node range and
// gather-computes acc += h[src] @ W[rel] with W in LDS (64KB rel-group passes,
// XOR-swizzled: <=2-way bank conflicts = free). Plain owner-exclusive stores.
// Self-loop+bias+relu(+pool) reuse the measured-correct finalize kernels.

#define IN_DIM 32
#define HID 64
#define NREL 16
#define NCLS 8
#define CHUNK 2048   // scan chunk: 256 threads x 8

__device__ __forceinline__ int rfl(int v) { return __builtin_amdgcn_readfirstlane(v); }
__device__ __forceinline__ int rl(int v, int l) { return __builtin_amdgcn_readlane(v, l); }

// ---------------- dst histogram + exclusive scan -> rowptr/filldst ----------------

__global__ void hist_dst_k(const int* __restrict__ dst, int* __restrict__ histd, int E) {
  for (int e = blockIdx.x * blockDim.x + threadIdx.x; e < E; e += gridDim.x * blockDim.x)
    atomicAdd(&histd[dst[e]], 1);
}

__global__ void scan1_k(const int* __restrict__ histd, int* __restrict__ csum, int N) {
  __shared__ int red[256];
  int t = threadIdx.x;
  int base = blockIdx.x * CHUNK + t * 8;
  int s = 0;
#pragma unroll
  for (int i = 0; i < 8; ++i) { int idx = base + i; s += (idx < N) ? histd[idx] : 0; }
  red[t] = s; __syncthreads();
  for (int off = 128; off > 0; off >>= 1) {
    if (t < off) red[t] += red[t + off];
    __syncthreads();
  }
  if (t == 0) csum[blockIdx.x] = red[0];
}

__global__ void scan2_k(const int* __restrict__ csum, int* __restrict__ cbase,
                        int* __restrict__ rowptr, int nchunks, int N) {
  if (threadIdx.x == 0) {
    int run = 0;
    for (int c = 0; c < nchunks; ++c) { cbase[c] = run; run += csum[c]; }
    rowptr[N] = run;   // == E
  }
}

__global__ void scan3_k(const int* __restrict__ histd, const int* __restrict__ cbase,
                        int* __restrict__ rowptr, int* __restrict__ filldst, int N) {
  __shared__ int ts[256];
  int t = threadIdx.x;
  int base = blockIdx.x * CHUNK + t * 8;
  int v[8]; int s = 0;
#pragma unroll
  for (int i = 0; i < 8; ++i) { int idx = base + i; int x = (idx < N) ? histd[idx] : 0; v[i] = x; s += x; }
  ts[t] = s; __syncthreads();
  int x = s;
  for (int off = 1; off < 256; off <<= 1) {
    int y = (t >= off) ? ts[t - off] : 0;
    __syncthreads();
    x += y; ts[t] = x;
    __syncthreads();
  }
  int run = cbase[blockIdx.x] + x - s;      // exclusive prefix for this thread
#pragma unroll
  for (int i = 0; i < 8; ++i) {
    int idx = base + i;
    if (idx < N) { rowptr[idx] = run; filldst[idx] = run; run += v[i]; }
  }
}

// dst-sorted packed edges: epack[q] = (src<<4)|rel
__global__ void scatter_pack(const int* __restrict__ src, const int* __restrict__ dst,
                             const int* __restrict__ rel, int* __restrict__ filldst,
                             int* __restrict__ epack, int E) {
  int e = blockIdx.x * blockDim.x + threadIdx.x;
  if (e < E) {
    int q = atomicAdd(&filldst[dst[e]], 1);
    epack[q] = (src[e] << 4) | rel[e];
  }
}

// ---------------- gather edge pass: GSZ rels staged in LDS (64KB) ----------------
// lane = output feature o. W[r][i][o] stored at lds[rl*K*64 + o*K + ((o&(K-1))^i)]
// -> read index fb0^i with fb0 = o*K + (o&(K-1)): <=2-way bank conflict (free).

template <int K, int GSZ, bool FIRST>
__global__ __launch_bounds__(512, 4)
void edge_pass(const float* __restrict__ hin, const int* __restrict__ epack,
               const int* __restrict__ rowptr, const float* __restrict__ W,
               float* __restrict__ out, int N, int g) {
  __shared__ float lw[GSZ * K * 64];
  const float* __restrict__ Wg = W + (size_t)g * GSZ * K * 64;
  for (int s = threadIdx.x; s < GSZ * K * 64; s += blockDim.x) {
    int rloc = s / (K * 64);
    int rem  = s - rloc * (K * 64);
    int i = rem >> 6;            // input row
    int o = rem & 63;            // output col
    lw[rloc * (K * 64) + o * K + ((o & (K - 1)) ^ i)] = Wg[s];
  }
  __syncthreads();

  const int lane = threadIdx.x & 63;
  const int nw  = gridDim.x * (blockDim.x >> 6);
  const int wid = blockIdx.x * (blockDim.x >> 6) + (threadIdx.x >> 6);
  const int per = (N + nw - 1) / nw;
  const int n0 = wid * per, n1 = min(N, n0 + per);
  const int fb0 = lane * K + (lane & (K - 1));
  const int SH = (GSZ == 8) ? 3 : 2;   // rel -> group shift

  for (int n = n0; n < n1; ++n) {
    const int j0 = rowptr[n], j1 = rowptr[n + 1];
    float acc = 0.f;
    bool any = false;
    for (int j = j0; j < j1; j += 64) {
      const int c = min(j1 - j, 64);
      const int bv = (lane < c) ? epack[j + lane] : 0;
      unsigned long long m = __ballot(lane < c && (((bv & 15) >> SH) == g));
      any |= (m != 0ull);
      while (m) {
        const int k = (int)__builtin_ctzll(m);
        m &= m - 1;
        const int v = rl(bv, k);                    // uniform
        const int s = v >> 4;
        const int rloc = (v & 15) - g * GSZ;
        const float4* __restrict__ row = (const float4*)(hin + (size_t)s * K);
        const float* __restrict__ lwp = lw + rloc * (K * 64);
        float a0 = 0.f, a1 = 0.f, a2 = 0.f, a3 = 0.f;
#pragma unroll
        for (int q = 0; q < K / 4; ++q) {
          float4 hv = row[q];                        // uniform addr -> broadcast
          a0 = fmaf(hv.x, lwp[fb0 ^ (4 * q + 0)], a0);
          a1 = fmaf(hv.y, lwp[fb0 ^ (4 * q + 1)], a1);
          a2 = fmaf(hv.z, lwp[fb0 ^ (4 * q + 2)], a2);
          a3 = fmaf(hv.w, lwp[fb0 ^ (4 * q + 3)], a3);
        }
        acc += (a0 + a1) + (a2 + a3);
      }
    }
    if (FIRST) out[(size_t)n * HID + lane] = acc;
    else if (any) out[(size_t)n * HID + lane] += acc;
  }
}

// ---------------- finalize: self-loop + bias + relu (measured-correct) ----------------

__global__ void finalize1(const float* __restrict__ agg, const float* __restrict__ h,
                          const float* __restrict__ Wl, const float* __restrict__ b,
                          float* __restrict__ h1, int N) {
  const int lane = threadIdx.x & 63;
  int wid = rfl((int)(blockIdx.x * (blockDim.x >> 6) + (threadIdx.x >> 6)));
  int nw = gridDim.x * (blockDim.x >> 6);
  float wl[IN_DIM];
#pragma unroll
  for (int i = 0; i < IN_DIM; ++i) wl[i] = Wl[i * HID + lane];
  float bv = b[lane];
  for (int n = wid; n < N; n += nw) {
    const float4* __restrict__ row = (const float4*)(h + (size_t)n * IN_DIM);
    float a0 = 0.f, a1 = 0.f, a2 = 0.f, a3 = 0.f;
#pragma unroll
    for (int i = 0; i < IN_DIM / 4; ++i) {
      float4 hv = row[i];
      a0 = fmaf(hv.x, wl[4 * i + 0], a0);
      a1 = fmaf(hv.y, wl[4 * i + 1], a1);
      a2 = fmaf(hv.z, wl[4 * i + 2], a2);
      a3 = fmaf(hv.w, wl[4 * i + 3], a3);
    }
    float v = agg[(size_t)n * HID + lane] + (a0 + a1) + (a2 + a3) + bv;
    h1[(size_t)n * HID + lane] = fmaxf(v, 0.f);
  }
}

__global__ void finalize2_pool(const float* __restrict__ agg, const float* __restrict__ h1,
                               const float* __restrict__ Wl, const float* __restrict__ b,
                               const int* __restrict__ n2g,
                               float* __restrict__ pooled, float* __restrict__ cnt, int N) {
  const int lane = threadIdx.x & 63;
  int wid = rfl((int)(blockIdx.x * (blockDim.x >> 6) + (threadIdx.x >> 6)));
  int nw = gridDim.x * (blockDim.x >> 6);
  int per = (N + nw - 1) / nw;
  int n0 = wid * per, n1 = min(N, n0 + per);
  if (n0 >= n1) return;
  float wl[HID];
#pragma unroll
  for (int i = 0; i < HID; ++i) wl[i] = Wl[i * HID + lane];
  float bv = b[lane];
  float psum = 0.f, pcnt = 0.f;
  int pg = -1;
  for (int n = n0; n < n1; ++n) {
    const float4* __restrict__ row = (const float4*)(h1 + (size_t)n * HID);
    float a0 = 0.f, a1 = 0.f, a2 = 0.f, a3 = 0.f;
#pragma unroll
    for (int i = 0; i < HID / 4; ++i) {
      float4 hv = row[i];
      a0 = fmaf(hv.x, wl[4 * i + 0], a0);
      a1 = fmaf(hv.y, wl[4 * i + 1], a1);
      a2 = fmaf(hv.z, wl[4 * i + 2], a2);
      a3 = fmaf(hv.w, wl[4 * i + 3], a3);
    }
    float v = agg[(size_t)n * HID + lane] + (a0 + a1) + (a2 + a3) + bv;
    v = fmaxf(v, 0.f);
    int g = rfl(n2g[n]);
    if (g != pg) {
      if (pg >= 0) {
        atomicAdd(&pooled[(size_t)pg * HID + lane], psum);
        if (lane == 0) atomicAdd(&cnt[pg], pcnt);
      }
      pg = g; psum = 0.f; pcnt = 0.f;
    }
    psum += v; pcnt += 1.f;
  }
  if (pg >= 0) {
    atomicAdd(&pooled[(size_t)pg * HID + lane], psum);
    if (lane == 0) atomicAdd(&cnt[pg], pcnt);
  }
}

// ---------------- classifier + softmax ----------------

__global__ void classifier(const float* __restrict__ pooled, const float* __restrict__ cnt,
                           const float* __restrict__ Wc, const float* __restrict__ bc,
                           float* __restrict__ out, int B) {
  int g = blockIdx.x * blockDim.x + threadIdx.x;
  if (g >= B) return;
  float c = fmaxf(cnt[g], 1.f);
  float lg[NCLS];
#pragma unroll
  for (int cc = 0; cc < NCLS; ++cc) lg[cc] = bc[cc];
  for (int k = 0; k < HID; ++k) {
    float hg = pooled[(size_t)g * HID + k] / c;
#pragma unroll
    for (int cc = 0; cc < NCLS; ++cc) lg[cc] = fmaf(hg, Wc[k * NCLS + cc], lg[cc]);
  }
  float m = lg[0];
#pragma unroll
  for (int cc = 1; cc < NCLS; ++cc) m = fmaxf(m, lg[cc]);
  float s = 0.f;
#pragma unroll
  for (int cc = 0; cc < NCLS; ++cc) { lg[cc] = __expf(lg[cc] - m); s += lg[cc]; }
  float inv = 1.f / s;
#pragma unroll
  for (int cc = 0; cc < NCLS; ++cc) out[(size_t)g * NCLS + cc] = lg[cc] * inv;
}

// ---------------- fallback (round-5 measured-correct atomic path) ----------------

__global__ void hist_rel(const int* __restrict__ rel, int* __restrict__ hist, int E) {
  __shared__ int lh[NREL];
  int tid = threadIdx.x;
  if (tid < NREL) lh[tid] = 0;
  __syncthreads();
  for (int e = blockIdx.x * blockDim.x + tid; e < E; e += gridDim.x * blockDim.x)
    atomicAdd(&lh[rel[e]], 1);
  __syncthreads();
  if (tid < NREL && lh[tid] > 0) atomicAdd(&hist[tid], lh[tid]);
}

__global__ void scan16(const int* __restrict__ hist, int* __restrict__ offs,
                       int* __restrict__ fill) {
  if (threadIdx.x == 0) {
    int o = 0;
    for (int r = 0; r < NREL; ++r) {
      offs[r] = o; fill[r] = o;
      o += (hist[r] + 63) & ~63;
    }
    offs[NREL] = o;
  }
}

__global__ void fill_pad(int* __restrict__ ssrc, int* __restrict__ sdst, int Epad, int N) {
  int i = blockIdx.x * blockDim.x + threadIdx.x;
  if (i < Epad) { ssrc[i] = 0; sdst[i] = N; }
}

__global__ void scatter_rel(const int* __restrict__ rel, const int* __restrict__ src,
                            const int* __restrict__ dst, int* __restrict__ fill,
                            int* __restrict__ ssrc, int* __restrict__ sdst, int E) {
  __shared__ int lc[NREL];
  __shared__ int lbase[NREL];
  int tid = threadIdx.x;
  if (tid < NREL) lc[tid] = 0;
  __syncthreads();
  int e = blockIdx.x * blockDim.x + tid;
  int r = 0, lo = 0;
  bool valid = (e < E);
  if (valid) { r = rel[e]; lo = atomicAdd(&lc[r], 1); }
  __syncthreads();
  if (tid < NREL && lc[tid] > 0) lbase[tid] = atomicAdd(&fill[tid], lc[tid]);
  __syncthreads();
  if (valid) { int p = lbase[r] + lo; ssrc[p] = src[e]; sdst[p] = dst[e]; }
}

template <int IN>
__global__ void edge_layer(const float* __restrict__ hin, const int* __restrict__ ssrc,
                           const int* __restrict__ sdst, const float* __restrict__ W,
                           const int* __restrict__ offs, float* __restrict__ agg,
                           int maxchunks) {
  const int lane = threadIdx.x & 63;
  int wid = rfl((int)(blockIdx.x * (blockDim.x >> 6) + (threadIdx.x >> 6)));
  if (wid >= maxchunks) return;
  const int base = wid * 64;
  int r = 0;
#pragma unroll
  for (int k = 1; k < NREL; ++k) r += (base >= offs[k]) ? 1 : 0;
  const float* Wr = W + (size_t)r * (IN * HID);
  float w[IN];
#pragma unroll
  for (int i = 0; i < IN; ++i) w[i] = Wr[i * HID + lane];
  const int myd = sdst[base + lane];
  const int mys = ssrc[base + lane];
#pragma unroll 4
  for (int k = 0; k < 64; ++k) {
    const int d = rl(myd, k);
    const int s = rl(mys, k);
    const float4* __restrict__ row = (const float4*)(hin + (size_t)s * IN);
    float a0 = 0.f, a1 = 0.f, a2 = 0.f, a3 = 0.f;
#pragma unroll
    for (int i = 0; i < IN / 4; ++i) {
      float4 hv = row[i];
      a0 = fmaf(hv.x, w[4 * i + 0], a0);
      a1 = fmaf(hv.y, w[4 * i + 1], a1);
      a2 = fmaf(hv.z, w[4 * i + 2], a2);
      a3 = fmaf(hv.w, w[4 * i + 3], a3);
    }
    atomicAdd(&agg[(size_t)d * HID + lane], (a0 + a1) + (a2 + a3));
  }
}

// ---------------- launch ----------------

extern "C" void kernel_launch(void* const* d_in, const int* in_sizes, int n_in,
                              void* d_out, int out_size, void* d_ws, size_t ws_size,
                              hipStream_t stream) {
  const float* h   = (const float*)d_in[0];
  const int* src   = (const int*)d_in[1];
  const int* dst   = (const int*)d_in[2];
  const int* rel   = (const int*)d_in[3];
  const int* n2g   = (const int*)d_in[4];
  const float* W1  = (const float*)d_in[5];
  const float* Wl1 = (const float*)d_in[6];
  const float* b1  = (const float*)d_in[7];
  const float* W2  = (const float*)d_in[8];
  const float* Wl2 = (const float*)d_in[9];
  const float* b2  = (const float*)d_in[10];
  const float* Wc  = (const float*)d_in[11];
  const float* bc  = (const float*)d_in[12];

  const int N = in_sizes[0] / IN_DIM;
  const int E = in_sizes[1];
  const int B = out_size / NCLS;
  const int nchunks = (N + CHUNK - 1) / CHUNK;

  // ---- v3 workspace layout (4B elements), ~59MB for N=100K/E=1.6M ----
  // tmp(N*64) | h1(N*64) | epack(E) | rowptr(N+1) | filldst(N) | histd(N)
  // | csum(nch) | cbase(nch) | pooled(B*64) | cnt(B)
  size_t need = (size_t)N * HID * 2 + (size_t)E + (size_t)(N + 1) + 2 * (size_t)N +
                2 * (size_t)nchunks + (size_t)B * HID + B + 64;
  if (ws_size >= need * 4) {
    float* tmp    = (float*)d_ws;
    float* h1     = tmp + (size_t)N * HID;
    int*   epack  = (int*)(h1 + (size_t)N * HID);
    int*   rowptr = epack + E;
    int*   filldst= rowptr + (N + 1);
    int*   histd  = filldst + N;
    int*   csum   = histd + N;
    int*   cbase  = csum + nchunks;
    float* pooled = (float*)(cbase + nchunks);
    float* cnt    = pooled + (size_t)B * HID;

    hipMemsetAsync(histd, 0, (size_t)N * sizeof(int), stream);
    hipMemsetAsync(pooled, 0, (size_t)(B * HID + B) * sizeof(float), stream);

    hist_dst_k<<<1024, 256, 0, stream>>>(dst, histd, E);
    scan1_k<<<nchunks, 256, 0, stream>>>(histd, csum, N);
    scan2_k<<<1, 64, 0, stream>>>(csum, cbase, rowptr, nchunks, N);
    scan3_k<<<nchunks, 256, 0, stream>>>(histd, cbase, rowptr, filldst, N);
    scatter_pack<<<(E + 255) / 256, 256, 0, stream>>>(src, dst, rel, filldst, epack, E);

    // layer 1: K=32, 8 rels/group -> 2 passes
    edge_pass<IN_DIM, 8, true ><<<512, 512, 0, stream>>>(h, epack, rowptr, W1, tmp, N, 0);
    edge_pass<IN_DIM, 8, false><<<512, 512, 0, stream>>>(h, epack, rowptr, W1, tmp, N, 1);
    finalize1<<<2048, 256, 0, stream>>>(tmp, h, Wl1, b1, h1, N);

    // layer 2: K=64, 4 rels/group -> 4 passes
    edge_pass<HID, 4, true ><<<512, 512, 0, stream>>>(h1, epack, rowptr, W2, tmp, N, 0);
    edge_pass<HID, 4, false><<<512, 512, 0, stream>>>(h1, epack, rowptr, W2, tmp, N, 1);
    edge_pass<HID, 4, false><<<512, 512, 0, stream>>>(h1, epack, rowptr, W2, tmp, N, 2);
    edge_pass<HID, 4, false><<<512, 512, 0, stream>>>(h1, epack, rowptr, W2, tmp, N, 3);
    finalize2_pool<<<2048, 256, 0, stream>>>(tmp, h1, Wl2, b2, n2g, pooled, cnt, N);

    classifier<<<(B + 127) / 128, 128, 0, stream>>>(pooled, cnt, Wc, bc, (float*)d_out, B);
    return;
  }

  // ---- fallback: round-5 measured-correct atomic path ----
  const int maxchunks = (E + 63) / 64 + NREL;
  const int Epad = maxchunks * 64;
  const int eblocks = (maxchunks + 3) / 4;
  float* agg    = (float*)d_ws;
  float* h1     = agg + (size_t)(N + 1) * HID;
  int*   ssrc   = (int*)(h1 + (size_t)N * HID);
  int*   sdst   = ssrc + Epad;
  int*   hist   = sdst + Epad;
  int*   offs   = hist + NREL;
  int*   fill   = offs + NREL + 1;
  float* pooled = (float*)(fill + NREL);
  float* cnt    = pooled + (size_t)B * HID;

  hipMemsetAsync(hist, 0, NREL * sizeof(int), stream);
  hipMemsetAsync(pooled, 0, (size_t)(B * HID + B) * sizeof(float), stream);
  fill_pad<<<(Epad + 255) / 256, 256, 0, stream>>>(ssrc, sdst, Epad, N);
  hist_rel<<<1024, 256, 0, stream>>>(rel, hist, E);
  scan16<<<1, 64, 0, stream>>>(hist, offs, fill);
  scatter_rel<<<(E + 255) / 256, 256, 0, stream>>>(rel, src, dst, fill, ssrc, sdst, E);
  hipMemsetAsync(agg, 0, (size_t)(N + 1) * HID * sizeof(float), stream);
  edge_layer<IN_DIM><<<eblocks, 256, 0, stream>>>(h, ssrc, sdst, W1, offs, agg, maxchunks);
  finalize1<<<2048, 256, 0, stream>>>(agg, h, Wl1, b1, h1, N);
  hipMemsetAsync(agg, 0, (size_t)(N + 1) * HID * sizeof(float), stream);
  edge_layer<HID><<<eblocks, 256, 0, stream>>>(h1, ssrc, sdst, W2, offs, agg, maxchunks);
  finalize2_pool<<<2048, 256, 0, stream>>>(agg, h1, Wl2, b2, n2g, pooled, cnt, N);
  classifier<<<(B + 127) / 128, 128, 0, stream>>>(pooled, cnt, Wc, bc, (float*)d_out, B);
}

// Round 10
// 1114.124 us; speedup vs baseline: 1.3392x; 1.3392x over previous
//
#include <hip/hip_runtime.h>
#include <hip/hip_bf16.h>

// R-GCN (2-layer) + mean-pool + linear + softmax, MI355X.
// v4: dst-sorted gather, 3 passes (was 6), 128KB LDS W-stage with transposed
// per-lane rows + store-side quad rotation (ds_read_b128, bank-spread), and a
// 2-edge pipelined inner loop for gather MLP. Round-9 rocprof: v3 was
// latency-bound (VALUBusy 32%, occ 33%, 0.58 TB/s effective gather) with a
// ds_read_b32 issue floor and 6x re-gather. Sort + finalize kernels unchanged
// (measured-correct). Atomic path kept as ws fallback.

#define IN_DIM 32
#define HID 64
#define NREL 16
#define NCLS 8
#define CHUNK 2048

__device__ __forceinline__ int rfl(int v) { return __builtin_amdgcn_readfirstlane(v); }
__device__ __forceinline__ int rl(int v, int l) { return __builtin_amdgcn_readlane(v, l); }

// ---------------- dst histogram + exclusive scan -> rowptr/filldst ----------------

__global__ void hist_dst_k(const int* __restrict__ dst, int* __restrict__ histd, int E) {
  for (int e = blockIdx.x * blockDim.x + threadIdx.x; e < E; e += gridDim.x * blockDim.x)
    atomicAdd(&histd[dst[e]], 1);
}

__global__ void scan1_k(const int* __restrict__ histd, int* __restrict__ csum, int N) {
  __shared__ int red[256];
  int t = threadIdx.x;
  int base = blockIdx.x * CHUNK + t * 8;
  int s = 0;
#pragma unroll
  for (int i = 0; i < 8; ++i) { int idx = base + i; s += (idx < N) ? histd[idx] : 0; }
  red[t] = s; __syncthreads();
  for (int off = 128; off > 0; off >>= 1) {
    if (t < off) red[t] += red[t + off];
    __syncthreads();
  }
  if (t == 0) csum[blockIdx.x] = red[0];
}

__global__ void scan2_k(const int* __restrict__ csum, int* __restrict__ cbase,
                        int* __restrict__ rowptr, int nchunks, int N) {
  if (threadIdx.x == 0) {
    int run = 0;
    for (int c = 0; c < nchunks; ++c) { cbase[c] = run; run += csum[c]; }
    rowptr[N] = run;
  }
}

__global__ void scan3_k(const int* __restrict__ histd, const int* __restrict__ cbase,
                        int* __restrict__ rowptr, int* __restrict__ filldst, int N) {
  __shared__ int ts[256];
  int t = threadIdx.x;
  int base = blockIdx.x * CHUNK + t * 8;
  int v[8]; int s = 0;
#pragma unroll
  for (int i = 0; i < 8; ++i) { int idx = base + i; int x = (idx < N) ? histd[idx] : 0; v[i] = x; s += x; }
  ts[t] = s; __syncthreads();
  int x = s;
  for (int off = 1; off < 256; off <<= 1) {
    int y = (t >= off) ? ts[t - off] : 0;
    __syncthreads();
    x += y; ts[t] = x;
    __syncthreads();
  }
  int run = cbase[blockIdx.x] + x - s;
#pragma unroll
  for (int i = 0; i < 8; ++i) {
    int idx = base + i;
    if (idx < N) { rowptr[idx] = run; filldst[idx] = run; run += v[i]; }
  }
}

__global__ void scatter_pack(const int* __restrict__ src, const int* __restrict__ dst,
                             const int* __restrict__ rel, int* __restrict__ filldst,
                             int* __restrict__ epack, int E) {
  int e = blockIdx.x * blockDim.x + threadIdx.x;
  if (e < E) {
    int q = atomicAdd(&filldst[dst[e]], 1);
    epack[q] = (src[e] << 4) | rel[e];
  }
}

// ---------------- v4 gather pass ----------------
// LDS: lw[rloc][o][i] transposed per-lane rows, quad-rotated on the STORE side:
//   float (rloc,i,o) -> lw[rloc*K*64 + o*K + 4*(((i>>2)+(o&M))&M) + (i&3)]
// Reader (lane o) reads physical quads sequentially via precomputed offB[t]
// (byte offsets) -> ds_read_b128, start banks spread by the rotation.
// h-row loads are plain sequential float4 (coalesced/broadcast).
// Inner loop: 2 edges per iteration, loads issued before FMAs (gather MLP).

template <int K, int GSZ, bool FIRST, bool FULL>
__global__ __launch_bounds__(1024, 1)
void edge_pass4(const float* __restrict__ hin, const int* __restrict__ epack,
                const int* __restrict__ rowptr, const float* __restrict__ W,
                float* __restrict__ out, int N, int g) {
  constexpr int Q = K / 4;                 // quads per row (8 or 16)
  constexpr int M = Q - 1;
  constexpr int QC = (Q < 8) ? Q : 8;      // chunk quads
  constexpr int NCH = Q / QC;              // 1 (K=32) or 2 (K=64)
  __shared__ float lw[GSZ * K * 64];       // 128 KB

  const float* __restrict__ Wg = W + (size_t)g * (GSZ * K * 64);
  for (int s = threadIdx.x; s < GSZ * K * 64; s += blockDim.x) {
    int rloc = s / (K * 64);
    int rem  = s - rloc * (K * 64);
    int i = rem >> 6;
    int o = rem & 63;
    lw[rloc * (K * 64) + o * K + 4 * (((i >> 2) + (o & M)) & M) + (i & 3)] = Wg[s];
  }
  __syncthreads();

  const int lane = threadIdx.x & 63;
  int offB[Q];                             // byte offsets, static-indexed
#pragma unroll
  for (int t = 0; t < Q; ++t)
    offB[t] = (lane * K + 4 * ((t + (lane & M)) & M)) * 4;

  const int nw  = gridDim.x * (blockDim.x >> 6);
  const int wid = blockIdx.x * (blockDim.x >> 6) + (threadIdx.x >> 6);
  const int per = (N + nw - 1) / nw;
  const int n0 = wid * per, n1 = min(N, n0 + per);
  const char* lwc = (const char*)lw;

  for (int n = n0; n < n1; ++n) {
    const int j0 = rowptr[n], j1 = rowptr[n + 1];
    float ax = 0.f, ay = 0.f, az = 0.f, aw = 0.f;
    bool any = false;
    for (int j = j0; j < j1; j += 64) {
      const int c = min(j1 - j, 64);
      const int bv = (lane < c) ? epack[j + lane] : 0;
      unsigned long long m;
      if (FULL) m = (c >= 64) ? ~0ull : ((1ull << c) - 1ull);
      else      m = __ballot((lane < c) && (((bv >> 3) & 1) == g));
      any |= (m != 0ull);
      while (m) {
        const int k0 = (int)__builtin_ctzll(m); m &= m - 1;
        const bool two = (m != 0ull);
        const int k1 = two ? (int)__builtin_ctzll(m) : k0;
        if (two) m &= m - 1;
        const int v0 = rl(bv, k0);
        const int v1 = rl(bv, k1);
        const float4* __restrict__ r0 = (const float4*)(hin + (size_t)(v0 >> 4) * K);
        const float4* __restrict__ r1 = (const float4*)(hin + (size_t)(v1 >> 4) * K);
        const int rb0 = (FULL ? (v0 & 15) : (v0 & 7)) * (K * 64 * 4);
        const int rb1 = (FULL ? (v1 & 15) : (v1 & 7)) * (K * 64 * 4);
        float bx = 0.f, by = 0.f, bz = 0.f, bw = 0.f;
        float4 A[QC], Bq[QC];
#pragma unroll
        for (int t = 0; t < QC; ++t) A[t] = r0[t];
#pragma unroll
        for (int t = 0; t < QC; ++t) Bq[t] = r1[t];
#pragma unroll
        for (int ch = 0; ch < NCH; ++ch) {
#pragma unroll
          for (int t = 0; t < QC; ++t) {
            const float4 wq = *(const float4*)(lwc + rb0 + offB[ch * QC + t]);
            ax = fmaf(A[t].x, wq.x, ax); ay = fmaf(A[t].y, wq.y, ay);
            az = fmaf(A[t].z, wq.z, az); aw = fmaf(A[t].w, wq.w, aw);
          }
          if (ch + 1 < NCH) {
#pragma unroll
            for (int t = 0; t < QC; ++t) A[t] = r0[(ch + 1) * QC + t];
          }
#pragma unroll
          for (int t = 0; t < QC; ++t) {
            const float4 wq = *(const float4*)(lwc + rb1 + offB[ch * QC + t]);
            bx = fmaf(Bq[t].x, wq.x, bx); by = fmaf(Bq[t].y, wq.y, by);
            bz = fmaf(Bq[t].z, wq.z, bz); bw = fmaf(Bq[t].w, wq.w, bw);
          }
          if (ch + 1 < NCH) {
#pragma unroll
            for (int t = 0; t < QC; ++t) Bq[t] = r1[(ch + 1) * QC + t];
          }
        }
        ax += two ? bx : 0.f; ay += two ? by : 0.f;
        az += two ? bz : 0.f; aw += two ? bw : 0.f;
      }
    }
    const float tot = (ax + ay) + (az + aw);
    if (FIRST) out[(size_t)n * HID + lane] = tot;
    else if (any) out[(size_t)n * HID + lane] += tot;
  }
}

// ---------------- finalize: self-loop + bias + relu (measured-correct) ----------------

__global__ void finalize1(const float* __restrict__ agg, const float* __restrict__ h,
                          const float* __restrict__ Wl, const float* __restrict__ b,
                          float* __restrict__ h1, int N) {
  const int lane = threadIdx.x & 63;
  int wid = rfl((int)(blockIdx.x * (blockDim.x >> 6) + (threadIdx.x >> 6)));
  int nw = gridDim.x * (blockDim.x >> 6);
  float wl[IN_DIM];
#pragma unroll
  for (int i = 0; i < IN_DIM; ++i) wl[i] = Wl[i * HID + lane];
  float bv = b[lane];
  for (int n = wid; n < N; n += nw) {
    const float4* __restrict__ row = (const float4*)(h + (size_t)n * IN_DIM);
    float a0 = 0.f, a1 = 0.f, a2 = 0.f, a3 = 0.f;
#pragma unroll
    for (int i = 0; i < IN_DIM / 4; ++i) {
      float4 hv = row[i];
      a0 = fmaf(hv.x, wl[4 * i + 0], a0);
      a1 = fmaf(hv.y, wl[4 * i + 1], a1);
      a2 = fmaf(hv.z, wl[4 * i + 2], a2);
      a3 = fmaf(hv.w, wl[4 * i + 3], a3);
    }
    float v = agg[(size_t)n * HID + lane] + (a0 + a1) + (a2 + a3) + bv;
    h1[(size_t)n * HID + lane] = fmaxf(v, 0.f);
  }
}

__global__ void finalize2_pool(const float* __restrict__ agg, const float* __restrict__ h1,
                               const float* __restrict__ Wl, const float* __restrict__ b,
                               const int* __restrict__ n2g,
                               float* __restrict__ pooled, float* __restrict__ cnt, int N) {
  const int lane = threadIdx.x & 63;
  int wid = rfl((int)(blockIdx.x * (blockDim.x >> 6) + (threadIdx.x >> 6)));
  int nw = gridDim.x * (blockDim.x >> 6);
  int per = (N + nw - 1) / nw;
  int n0 = wid * per, n1 = min(N, n0 + per);
  if (n0 >= n1) return;
  float wl[HID];
#pragma unroll
  for (int i = 0; i < HID; ++i) wl[i] = Wl[i * HID + lane];
  float bv = b[lane];
  float psum = 0.f, pcnt = 0.f;
  int pg = -1;
  for (int n = n0; n < n1; ++n) {
    const float4* __restrict__ row = (const float4*)(h1 + (size_t)n * HID);
    float a0 = 0.f, a1 = 0.f, a2 = 0.f, a3 = 0.f;
#pragma unroll
    for (int i = 0; i < HID / 4; ++i) {
      float4 hv = row[i];
      a0 = fmaf(hv.x, wl[4 * i + 0], a0);
      a1 = fmaf(hv.y, wl[4 * i + 1], a1);
      a2 = fmaf(hv.z, wl[4 * i + 2], a2);
      a3 = fmaf(hv.w, wl[4 * i + 3], a3);
    }
    float v = agg[(size_t)n * HID + lane] + (a0 + a1) + (a2 + a3) + bv;
    v = fmaxf(v, 0.f);
    int g = rfl(n2g[n]);
    if (g != pg) {
      if (pg >= 0) {
        atomicAdd(&pooled[(size_t)pg * HID + lane], psum);
        if (lane == 0) atomicAdd(&cnt[pg], pcnt);
      }
      pg = g; psum = 0.f; pcnt = 0.f;
    }
    psum += v; pcnt += 1.f;
  }
  if (pg >= 0) {
    atomicAdd(&pooled[(size_t)pg * HID + lane], psum);
    if (lane == 0) atomicAdd(&cnt[pg], pcnt);
  }
}

// ---------------- classifier + softmax ----------------

__global__ void classifier(const float* __restrict__ pooled, const float* __restrict__ cnt,
                           const float* __restrict__ Wc, const float* __restrict__ bc,
                           float* __restrict__ out, int B) {
  int g = blockIdx.x * blockDim.x + threadIdx.x;
  if (g >= B) return;
  float c = fmaxf(cnt[g], 1.f);
  float lg[NCLS];
#pragma unroll
  for (int cc = 0; cc < NCLS; ++cc) lg[cc] = bc[cc];
  for (int k = 0; k < HID; ++k) {
    float hg = pooled[(size_t)g * HID + k] / c;
#pragma unroll
    for (int cc = 0; cc < NCLS; ++cc) lg[cc] = fmaf(hg, Wc[k * NCLS + cc], lg[cc]);
  }
  float m = lg[0];
#pragma unroll
  for (int cc = 1; cc < NCLS; ++cc) m = fmaxf(m, lg[cc]);
  float s = 0.f;
#pragma unroll
  for (int cc = 0; cc < NCLS; ++cc) { lg[cc] = __expf(lg[cc] - m); s += lg[cc]; }
  float inv = 1.f / s;
#pragma unroll
  for (int cc = 0; cc < NCLS; ++cc) out[(size_t)g * NCLS + cc] = lg[cc] * inv;
}

// ---------------- fallback (round-5 measured-correct atomic path) ----------------

__global__ void hist_rel(const int* __restrict__ rel, int* __restrict__ hist, int E) {
  __shared__ int lh[NREL];
  int tid = threadIdx.x;
  if (tid < NREL) lh[tid] = 0;
  __syncthreads();
  for (int e = blockIdx.x * blockDim.x + tid; e < E; e += gridDim.x * blockDim.x)
    atomicAdd(&lh[rel[e]], 1);
  __syncthreads();
  if (tid < NREL && lh[tid] > 0) atomicAdd(&hist[tid], lh[tid]);
}

__global__ void scan16(const int* __restrict__ hist, int* __restrict__ offs,
                       int* __restrict__ fill) {
  if (threadIdx.x == 0) {
    int o = 0;
    for (int r = 0; r < NREL; ++r) {
      offs[r] = o; fill[r] = o;
      o += (hist[r] + 63) & ~63;
    }
    offs[NREL] = o;
  }
}

__global__ void fill_pad(int* __restrict__ ssrc, int* __restrict__ sdst, int Epad, int N) {
  int i = blockIdx.x * blockDim.x + threadIdx.x;
  if (i < Epad) { ssrc[i] = 0; sdst[i] = N; }
}

__global__ void scatter_rel(const int* __restrict__ rel, const int* __restrict__ src,
                            const int* __restrict__ dst, int* __restrict__ fill,
                            int* __restrict__ ssrc, int* __restrict__ sdst, int E) {
  __shared__ int lc[NREL];
  __shared__ int lbase[NREL];
  int tid = threadIdx.x;
  if (tid < NREL) lc[tid] = 0;
  __syncthreads();
  int e = blockIdx.x * blockDim.x + tid;
  int r = 0, lo = 0;
  bool valid = (e < E);
  if (valid) { r = rel[e]; lo = atomicAdd(&lc[r], 1); }
  __syncthreads();
  if (tid < NREL && lc[tid] > 0) lbase[tid] = atomicAdd(&fill[tid], lc[tid]);
  __syncthreads();
  if (valid) { int p = lbase[r] + lo; ssrc[p] = src[e]; sdst[p] = dst[e]; }
}

template <int IN>
__global__ void edge_layer(const float* __restrict__ hin, const int* __restrict__ ssrc,
                           const int* __restrict__ sdst, const float* __restrict__ W,
                           const int* __restrict__ offs, float* __restrict__ agg,
                           int maxchunks) {
  const int lane = threadIdx.x & 63;
  int wid = rfl((int)(blockIdx.x * (blockDim.x >> 6) + (threadIdx.x >> 6)));
  if (wid >= maxchunks) return;
  const int base = wid * 64;
  int r = 0;
#pragma unroll
  for (int k = 1; k < NREL; ++k) r += (base >= offs[k]) ? 1 : 0;
  const float* Wr = W + (size_t)r * (IN * HID);
  float w[IN];
#pragma unroll
  for (int i = 0; i < IN; ++i) w[i] = Wr[i * HID + lane];
  const int myd = sdst[base + lane];
  const int mys = ssrc[base + lane];
#pragma unroll 4
  for (int k = 0; k < 64; ++k) {
    const int d = rl(myd, k);
    const int s = rl(mys, k);
    const float4* __restrict__ row = (const float4*)(hin + (size_t)s * IN);
    float a0 = 0.f, a1 = 0.f, a2 = 0.f, a3 = 0.f;
#pragma unroll
    for (int i = 0; i < IN / 4; ++i) {
      float4 hv = row[i];
      a0 = fmaf(hv.x, w[4 * i + 0], a0);
      a1 = fmaf(hv.y, w[4 * i + 1], a1);
      a2 = fmaf(hv.z, w[4 * i + 2], a2);
      a3 = fmaf(hv.w, w[4 * i + 3], a3);
    }
    atomicAdd(&agg[(size_t)d * HID + lane], (a0 + a1) + (a2 + a3));
  }
}

// ---------------- launch ----------------

extern "C" void kernel_launch(void* const* d_in, const int* in_sizes, int n_in,
                              void* d_out, int out_size, void* d_ws, size_t ws_size,
                              hipStream_t stream) {
  const float* h   = (const float*)d_in[0];
  const int* src   = (const int*)d_in[1];
  const int* dst   = (const int*)d_in[2];
  const int* rel   = (const int*)d_in[3];
  const int* n2g   = (const int*)d_in[4];
  const float* W1  = (const float*)d_in[5];
  const float* Wl1 = (const float*)d_in[6];
  const float* b1  = (const float*)d_in[7];
  const float* W2  = (const float*)d_in[8];
  const float* Wl2 = (const float*)d_in[9];
  const float* b2  = (const float*)d_in[10];
  const float* Wc  = (const float*)d_in[11];
  const float* bc  = (const float*)d_in[12];

  const int N = in_sizes[0] / IN_DIM;
  const int E = in_sizes[1];
  const int B = out_size / NCLS;
  const int nchunks = (N + CHUNK - 1) / CHUNK;

  // ---- v4 workspace layout (4B elements), ~59MB ----
  size_t need = (size_t)N * HID * 2 + (size_t)E + (size_t)(N + 1) + 2 * (size_t)N +
                2 * (size_t)nchunks + (size_t)B * HID + B + 64;
  if (ws_size >= need * 4) {
    float* tmp    = (float*)d_ws;
    float* h1     = tmp + (size_t)N * HID;
    int*   epack  = (int*)(h1 + (size_t)N * HID);
    int*   rowptr = epack + E;
    int*   filldst= rowptr + (N + 1);
    int*   histd  = filldst + N;
    int*   csum   = histd + N;
    int*   cbase  = csum + nchunks;
    float* pooled = (float*)(cbase + nchunks);
    float* cnt    = pooled + (size_t)B * HID;

    hipMemsetAsync(histd, 0, (size_t)N * sizeof(int), stream);
    hipMemsetAsync(pooled, 0, (size_t)(B * HID + B) * sizeof(float), stream);

    hist_dst_k<<<1024, 256, 0, stream>>>(dst, histd, E);
    scan1_k<<<nchunks, 256, 0, stream>>>(histd, csum, N);
    scan2_k<<<1, 64, 0, stream>>>(csum, cbase, rowptr, nchunks, N);
    scan3_k<<<nchunks, 256, 0, stream>>>(histd, cbase, rowptr, filldst, N);
    scatter_pack<<<(E + 255) / 256, 256, 0, stream>>>(src, dst, rel, filldst, epack, E);

    // layer 1: all 16 rels in 128KB LDS -> single full pass
    edge_pass4<IN_DIM, 16, true, true><<<256, 1024, 0, stream>>>(h, epack, rowptr, W1,
                                                                 tmp, N, 0);
    finalize1<<<2048, 256, 0, stream>>>(tmp, h, Wl1, b1, h1, N);

    // layer 2: 8 rels per pass (128KB) -> 2 passes
    edge_pass4<HID, 8, true,  false><<<256, 1024, 0, stream>>>(h1, epack, rowptr, W2,
                                                               tmp, N, 0);
    edge_pass4<HID, 8, false, false><<<256, 1024, 0, stream>>>(h1, epack, rowptr, W2,
                                                               tmp, N, 1);
    finalize2_pool<<<2048, 256, 0, stream>>>(tmp, h1, Wl2, b2, n2g, pooled, cnt, N);

    classifier<<<(B + 127) / 128, 128, 0, stream>>>(pooled, cnt, Wc, bc, (float*)d_out, B);
    return;
  }

  // ---- fallback: round-5 measured-correct atomic path ----
  const int maxchunks = (E + 63) / 64 + NREL;
  const int Epad = maxchunks * 64;
  const int eblocks = (maxchunks + 3) / 4;
  float* agg    = (float*)d_ws;
  float* h1     = agg + (size_t)(N + 1) * HID;
  int*   ssrc   = (int*)(h1 + (size_t)N * HID);
  int*   sdst   = ssrc + Epad;
  int*   hist   = sdst + Epad;
  int*   offs   = hist + NREL;
  int*   fill   = offs + NREL + 1;
  float* pooled = (float*)(fill + NREL);
  float* cnt    = pooled + (size_t)B * HID;

  hipMemsetAsync(hist, 0, NREL * sizeof(int), stream);
  hipMemsetAsync(pooled, 0, (size_t)(B * HID + B) * sizeof(float), stream);
  fill_pad<<<(Epad + 255) / 256, 256, 0, stream>>>(ssrc, sdst, Epad, N);
  hist_rel<<<1024, 256, 0, stream>>>(rel, hist, E);
  scan16<<<1, 64, 0, stream>>>(hist, offs, fill);
  scatter_rel<<<(E + 255) / 256, 256, 0, stream>>>(rel, src, dst, fill, ssrc, sdst, E);
  hipMemsetAsync(agg, 0, (size_t)(N + 1) * HID * sizeof(float), stream);
  edge_layer<IN_DIM><<<eblocks, 256, 0, stream>>>(h, ssrc, sdst, W1, offs, agg, maxchunks);
  finalize1<<<2048, 256, 0, stream>>>(agg, h, Wl1, b1, h1, N);
  hipMemsetAsync(agg, 0, (size_t)(N + 1) * HID * sizeof(float), stream);
  edge_layer<HID><<<eblocks, 256, 0, stream>>>(h1, ssrc, sdst, W2, offs, agg, maxchunks);
  finalize2_pool<<<2048, 256, 0, stream>>>(agg, h1, Wl2, b2, n2g, pooled, cnt, N);
  classifier<<<(B + 127) / 128, 128, 0, stream>>>(pooled, cnt, Wc, bc, (float*)d_out, B);
}